// Round 7
// baseline (29964.487 us; speedup 1.0000x reference)
//
#include <hip/hip_runtime.h>
#include <stdint.h>

typedef _Float16 f16x8 __attribute__((ext_vector_type(8)));
typedef _Float16 f16x4 __attribute__((ext_vector_type(4)));
typedef float f32x4 __attribute__((ext_vector_type(4)));

static __device__ __forceinline__ float bf2f(unsigned short u) {
  return __uint_as_float(((unsigned int)u) << 16);
}
static __device__ __forceinline__ unsigned short f2bf(float f) {
  unsigned int u = __float_as_uint(f);
  u = (u + 0x7FFFu + ((u >> 16) & 1u)) >> 16;  // RNE
  return (unsigned short)u;
}
static __device__ __forceinline__ unsigned short f2h(float f) {
  _Float16 h = (_Float16)f;
  return __builtin_bit_cast(unsigned short, h);
}
static __device__ __forceinline__ float h2f(unsigned short b) {
  _Float16 h = __builtin_bit_cast(_Float16, b);
  return (float)h;
}
static __device__ __forceinline__ float sigm(float x) { return 1.0f / (1.0f + __expf(-x)); }
static __device__ __forceinline__ float tanh_fast(float x) {
  float ax = fabsf(x);
  float e = __expf(-2.0f * ax);
  float r = (1.0f - e) / (1.0f + e);
  return copysignf(r, x);
}

// ---------------- dtype probe: 1 = bf16 inputs, 0 = f32 inputs ----------------
__global__ void probe_kernel(const unsigned int* __restrict__ raw, unsigned int* __restrict__ dflag) {
  __shared__ int s;
  int tid = threadIdx.x;
  if (tid == 0) s = 0;
  __syncthreads();
  int v = 0;
  for (int k = 0; k < 4; ++k) {
    unsigned int d = raw[2048 + tid * 4 + k];
    unsigned int lo = d & 0xFFFFu, ex = (lo >> 7) & 0xFFu;
    if (lo == 0u || (ex >= 0x40u && ex <= 0x7Cu)) v++;
  }
  atomicAdd(&s, v);
  __syncthreads();
  if (tid == 0) dflag[0] = (s >= 614) ? 1u : 0u;
}

// ---------------- embedding -> f16 act0 [32768][448], pad cols -> 0 ----------
__global__ void embed_kernel(const int* __restrict__ x, const void* __restrict__ emb,
                             unsigned short* __restrict__ act, const unsigned int* __restrict__ dflag) {
  int idx = blockIdx.x * 256 + threadIdx.x;  // 32768 rows * 56 chunks
  int row = idx / 56, c = idx % 56;
  unsigned short* dst = act + (size_t)row * 448 + c * 8;
  union { uint4 v; unsigned short s[8]; } o;
  if (c < 50) {
    int tok = x[row];
    if (dflag[0]) {
      const unsigned short* e = (const unsigned short*)emb + (size_t)tok * 400 + c * 8;
      union { uint4 v; unsigned short s[8]; } r; r.v = *(const uint4*)e;
#pragma unroll
      for (int k = 0; k < 8; ++k) o.s[k] = f2h(bf2f(r.s[k]));
    } else {
      const float* e = (const float*)emb + (size_t)tok * 400 + c * 8;
      float4 r0 = *(const float4*)e, r1 = *(const float4*)(e + 4);
      const float* p0 = (const float*)&r0; const float* p1 = (const float*)&r1;
#pragma unroll
      for (int k = 0; k < 4; ++k) { o.s[k] = f2h(p0[k]); o.s[4 + k] = f2h(p1[k]); }
    }
  } else {
    o.v.x = o.v.y = o.v.z = o.v.w = 0u;
  }
  *(uint4*)dst = o.v;
}

// ------------- weights/bias -> GROUP-MAJOR padded f16 layouts -----------------
// Row j' = G*64 + q*16 + u  <->  unit i = G*16+u, gate q (i,f,g,o).
__global__ void prep_kernel(const void* __restrict__ wih, const void* __restrict__ whh,
                            const void* __restrict__ bih, const void* __restrict__ bhh,
                            unsigned short* __restrict__ WihG, unsigned short* __restrict__ WhhG,
                            float* __restrict__ biasG, int H, int HPo, int din, int dpIn,
                            const unsigned int* __restrict__ dflag) {
  int nb = 4 * HPo, bid = blockIdx.x, tid = threadIdx.x;
  bool isf32 = (dflag[0] == 0u);
  if (bid < 2 * nb) {
    bool ih = bid < nb;
    int j = ih ? bid : bid - nb;
    int i = (j >> 6) * 16 + (j & 15), q = (j >> 4) & 3;
    int cdst = ih ? dpIn : HPo, csrc = ih ? din : H;
    unsigned short* dst = (ih ? WihG : WhhG) + (size_t)j * cdst;
    bool valid = i < H;
    const void* w = ih ? wih : whh;
    for (int m = tid; m < cdst; m += 256) {
      unsigned short v = 0;
      if (valid && m < csrc) {
        if (isf32) v = f2h(((const float*)w)[(size_t)(q * H + i) * csrc + m]);
        else       v = f2h(bf2f(((const unsigned short*)w)[(size_t)(q * H + i) * csrc + m]));
      }
      dst[m] = v;
    }
  } else {
    for (int m = tid; m < nb; m += 256) {
      int i = (m >> 6) * 16 + (m & 15), q = (m >> 4) & 3;
      float v = 0.0f;
      if (i < H) {
        if (isf32) v = ((const float*)bih)[q * H + i] + ((const float*)bhh)[q * H + i];
        else       v = bf2f(((const unsigned short*)bih)[q * H + i]) + bf2f(((const unsigned short*)bhh)[q * H + i]);
      }
      biasG[m] = v;
    }
  }
}

// ---------------- final unpad: act3 f16 [.][448] -> d_out (bf16 or f32) -------
__global__ void unpad_kernel(const unsigned short* __restrict__ act, void* __restrict__ out,
                             const unsigned int* __restrict__ dflag) {
  int idx = blockIdx.x * 256 + threadIdx.x;  // 32768 * 50
  int row = idx / 50, c = idx % 50;
  const unsigned short* src = act + (size_t)row * 448 + c * 8;
  union { uint4 v; unsigned short s[8]; } u; u.v = *(const uint4*)src;
  if (dflag[0]) {
    union { uint4 v; unsigned short s[8]; } o;
#pragma unroll
    for (int k = 0; k < 8; ++k) o.s[k] = f2bf(h2f(u.s[k]));
    *(uint4*)((unsigned short*)out + (size_t)row * 400 + c * 8) = o.v;
  } else {
    float4 o0, o1;
    float* p0 = (float*)&o0; float* p1 = (float*)&o1;
#pragma unroll
    for (int k = 0; k < 4; ++k) { p0[k] = h2f(u.s[k]); p1[k] = h2f(u.s[4 + k]); }
    float* dst = (float*)out + (size_t)row * 400 + c * 8;
    *(float4*)dst = o0; *(float4*)(dst + 4) = o1;
  }
}

// ------------- chunked GEMM: gx = act_chunk @ WihG^T, cell-layout f16 ---------
// gx[((size_t)G*chrows + m)*64 + u*4 + q], G=n>>6, q=(n>>4)&3, u=n&15.
__global__ __launch_bounds__(256, 1) void gemm_xw_kernel(
    const unsigned short* __restrict__ A, const unsigned short* __restrict__ B,
    unsigned short* __restrict__ gx, int K, int chrows) {
  __shared__ unsigned short Asm[128 * 32], Bsm[128 * 32];  // 8KB each, XOR-swizzled
  const int tid = threadIdx.x, lane = tid & 63, wv = tid >> 6;
  const int bm0 = blockIdx.x * 128, bn0 = blockIdx.y * 128;
  f32x4 acc[2][8] = {};
  const int nkt = K >> 5;
  for (int kt = 0; kt < nkt; ++kt) {
    __syncthreads();
#pragma unroll
    for (int j = 0; j < 2; ++j) {
      int idx = tid * 2 + j, r = idx >> 2, c4 = idx & 3;
      uint4 va = *(const uint4*)(A + (size_t)(bm0 + r) * K + kt * 32 + c4 * 8);
      uint4 vb = *(const uint4*)(B + (size_t)(bn0 + r) * K + kt * 32 + c4 * 8);
      int off = (r * 64 + c4 * 16) ^ ((r & 7) << 4);
      *(uint4*)((char*)Asm + off) = va;
      *(uint4*)((char*)Bsm + off) = vb;
    }
    __syncthreads();
    f16x8 af[2], bf[8];
#pragma unroll
    for (int rt = 0; rt < 2; ++rt) {
      int arow = wv * 32 + rt * 16 + (lane & 15);
      int off = (arow * 64 + ((lane >> 4) << 4)) ^ ((arow & 7) << 4);
      af[rt] = *(const f16x8*)((char*)Asm + off);
    }
#pragma unroll
    for (int ct = 0; ct < 8; ++ct) {
      int brow = ct * 16 + (lane & 15);
      int off = (brow * 64 + ((lane >> 4) << 4)) ^ ((brow & 7) << 4);
      bf[ct] = *(const f16x8*)((char*)Bsm + off);
    }
#pragma unroll
    for (int rt = 0; rt < 2; ++rt)
#pragma unroll
      for (int ct = 0; ct < 8; ++ct)
        acc[rt][ct] = __builtin_amdgcn_mfma_f32_16x16x32_f16(af[rt], bf[ct], acc[rt][ct], 0, 0, 0);
  }
#pragma unroll
  for (int ct = 0; ct < 8; ++ct) {
    int n = bn0 + ct * 16 + (lane & 15);
    int G = n >> 6, c = n & 63;
    int cellcol = (c & 15) * 4 + (c >> 4);
#pragma unroll
    for (int rt = 0; rt < 2; ++rt) {
#pragma unroll
      for (int reg = 0; reg < 4; ++reg) {
        int m = bm0 + wv * 32 + rt * 16 + ((lane >> 4) << 2) + reg;
        gx[((size_t)G * chrows + m) * 64 + cellcol] = f2h(acc[rt][ct][reg]);
      }
    }
  }
}

// ---------------- recurrent phase: h-part only, chunked, weights in VGPR -------
// Block G owns 16 hidden units (64 gate-cols). 512 threads = 8 waves:
// nq = wv&3 (16-col group), kq = wv>>2 (K half). Each wave: 4 m-tiles x KT k-tiles.
// MODE: 0=full, 1=sync-skeleton, 2=compute-no-wait, 3=compute-no-hload-no-wait.
template <int HP, int MODE>
static __device__ __forceinline__ void rec_body(
    const unsigned short* __restrict__ gxAll, unsigned short* __restrict__ actOut,
    const unsigned short* __restrict__ WhhG, const float* __restrict__ biasG,
    unsigned int* __restrict__ cnt, float* __restrict__ cstate,
    int t0, int TS, int chrows) {
  constexpr int NB = HP / 16;              // blocks
  constexpr int KS = HP / 2, KT = KS / 32; // 18 or 7 k-tiles per wave
  constexpr int KB1 = (KT + 1) / 2, KB2 = KT - KB1;
  constexpr int GSTR = 68;                 // Gp row stride (2-way banks)
  extern __shared__ char smem[];
  float* Gp = (float*)smem;                // [2][64][GSTR] f32
  const int tid = threadIdx.x, lane = tid & 63, wv = tid >> 6;
  const int nq = wv & 3, kq = wv >> 2;
  const int lrow = lane & 15, kc8 = (lane >> 4) << 3;
  const int G = blockIdx.x;
  const int urow = tid >> 3, ui = tid & 7;
  const int rmask = chrows - 1;

  float bs0[4], bs1[4];
  float creg0 = 0.0f, creg1 = 0.0f;
  f16x8 wreg[KT];
  f16x4 gxv0 = {}, gxv1 = {};
  if constexpr (MODE != 1) {
    const unsigned short* wp = WhhG + ((size_t)(G * 64 + nq * 16 + lrow)) * HP + kq * KS + kc8;
#pragma unroll
    for (int kt = 0; kt < KT; ++kt) wreg[kt] = *(const f16x8*)(wp + kt * 32);
#pragma unroll
    for (int q = 0; q < 4; ++q) {
      bs0[q] = biasG[G * 64 + q * 16 + ui];
      bs1[q] = biasG[G * 64 + q * 16 + ui + 8];
    }
    if (t0 > 0) {
      creg0 = cstate[urow * HP + G * 16 + ui];
      creg1 = cstate[urow * HP + G * 16 + ui + 8];
    }
    gxv0 = *(const f16x4*)(gxAll + ((size_t)G * chrows + urow) * 64 + ui * 4);
    gxv1 = *(const f16x4*)(gxAll + ((size_t)G * chrows + urow) * 64 + (ui + 8) * 4);
  } else {
#pragma unroll
    for (int q = 0; q < 4; ++q) { bs0[q] = 0.f; bs1[q] = 0.f; }
#pragma unroll
    for (int kt = 0; kt < KT; ++kt) wreg[kt] = f16x8{};
  }
  __syncthreads();

  const int tend = t0 + TS;
  for (int t = t0; t < tend; ++t) {
    // ---- wait for all blocks' h(t-1)
    if constexpr (MODE == 0 || MODE == 1) {
      if (t > 0) {
        while (true) {
          int ok = 1;
          if (tid < 8) {
            unsigned perl = (unsigned)(NB >> 3) + ((tid < (NB & 7)) ? 1u : 0u);
            ok = (__hip_atomic_load(cnt + tid * 32, __ATOMIC_RELAXED, __HIP_MEMORY_SCOPE_AGENT) >= perl * (unsigned)t);
          }
          if (__syncthreads_and(ok)) break;
          __builtin_amdgcn_s_sleep(1);
        }
        asm volatile("" ::: "memory");
      }
    }
    // ---- h-part MFMA into Gp partials
    if constexpr (MODE != 1) {
      if (t > 0) {
#pragma unroll
        for (int mt = 0; mt < 4; ++mt) {
          f32x4 a = {0.f, 0.f, 0.f, 0.f};
          if constexpr (MODE == 3) {
#pragma unroll
            for (int kt = 0; kt < KT; ++kt)
              a = __builtin_amdgcn_mfma_f32_16x16x32_f16(wreg[kt], wreg[kt], a, 0, 0, 0);
          } else {
            const unsigned short* hp =
                actOut + ((size_t)(t - 1) * 64 + mt * 16 + lrow) * HP + kq * KS + kc8;
            {
              f16x8 hv[KB1];
#pragma unroll
              for (int i = 0; i < KB1; ++i) hv[i] = *(const f16x8*)(hp + i * 32);
#pragma unroll
              for (int i = 0; i < KB1; ++i)
                a = __builtin_amdgcn_mfma_f32_16x16x32_f16(hv[i], wreg[i], a, 0, 0, 0);
            }
            {
              f16x8 hv[KB2 > 0 ? KB2 : 1];
#pragma unroll
              for (int i = 0; i < KB2; ++i) hv[i] = *(const f16x8*)(hp + (KB1 + i) * 32);
#pragma unroll
              for (int i = 0; i < KB2; ++i)
                a = __builtin_amdgcn_mfma_f32_16x16x32_f16(hv[i], wreg[KB1 + i], a, 0, 0, 0);
            }
          }
          const int br = mt * 16 + (lane >> 4) * 4;
#pragma unroll
          for (int r = 0; r < 4; ++r)
            Gp[(kq * 64 + br + r) * GSTR + nq * 16 + lrow] = a[r];
        }
      }
    }
    __syncthreads();
    // ---- reduce + gate update (two units per thread)
    unsigned short hb0 = 0, hb1 = 0;
    if constexpr (MODE != 1) {
      float gi0 = (float)gxv0[0] + bs0[0], gf0 = (float)gxv0[1] + bs0[1];
      float gg0 = (float)gxv0[2] + bs0[2], go0 = (float)gxv0[3] + bs0[3];
      float gi1 = (float)gxv1[0] + bs1[0], gf1 = (float)gxv1[1] + bs1[1];
      float gg1 = (float)gxv1[2] + bs1[2], go1 = (float)gxv1[3] + bs1[3];
      if (t > 0) {
#pragma unroll
        for (int k = 0; k < 2; ++k) {
          const int base = (k * 64 + urow) * GSTR + ui;
          gi0 += Gp[base];      gf0 += Gp[base + 16];
          gg0 += Gp[base + 32]; go0 += Gp[base + 48];
          gi1 += Gp[base + 8];  gf1 += Gp[base + 24];
          gg1 += Gp[base + 40]; go1 += Gp[base + 56];
        }
      }
      float ig0 = sigm(gi0), fg0 = sigm(gf0), gt0 = tanh_fast(gg0), og0 = sigm(go0);
      creg0 = fg0 * creg0 + ig0 * gt0;
      hb0 = f2h(og0 * tanh_fast(creg0));
      float ig1 = sigm(gi1), fg1 = sigm(gf1), gt1 = tanh_fast(gg1), og1 = sigm(go1);
      creg1 = fg1 * creg1 + ig1 * gt1;
      hb1 = f2h(og1 * tanh_fast(creg1));
      if (t + 1 < tend) {  // prefetch next gx cells
        const int nr = ((t + 1 - t0) * 64 + urow) & rmask;
        gxv0 = *(const f16x4*)(gxAll + ((size_t)G * chrows + nr) * 64 + ui * 4);
        gxv1 = *(const f16x4*)(gxAll + ((size_t)G * chrows + nr) * 64 + (ui + 8) * 4);
      }
    }
    int o0 = __shfl_xor((int)hb0, 1), o1 = __shfl_xor((int)hb1, 1);
    if ((ui & 1) == 0) {
      unsigned short* base = actOut + ((size_t)t * 64 + urow) * HP + G * 16;
      unsigned int pk0 = ((unsigned)hb0 & 0xFFFFu) | ((unsigned)o0 << 16);
      unsigned int pk1 = ((unsigned)hb1 & 0xFFFFu) | ((unsigned)o1 << 16);
      __hip_atomic_store((unsigned int*)(base + ui), pk0, __ATOMIC_RELAXED, __HIP_MEMORY_SCOPE_AGENT);
      __hip_atomic_store((unsigned int*)(base + ui + 8), pk1, __ATOMIC_RELAXED, __HIP_MEMORY_SCOPE_AGENT);
    }
    __syncthreads();  // implicit vmcnt(0) drains all waves' h stores
    if (tid == 0)
      __hip_atomic_fetch_add(cnt + (G & 7) * 32, 1u, __ATOMIC_RELEASE, __HIP_MEMORY_SCOPE_AGENT);
  }
  if constexpr (MODE == 0) {
    cstate[urow * HP + G * 16 + ui] = creg0;
    cstate[urow * HP + G * 16 + ui + 8] = creg1;
  }
}

__global__ __launch_bounds__(512, 2) void lstm_rec1152(
    const unsigned short* __restrict__ gxAll, unsigned short* __restrict__ actOut,
    const unsigned short* __restrict__ WhhG, const float* __restrict__ biasG,
    unsigned int* __restrict__ cnt, float* __restrict__ cstate, int t0, int TS, int chrows) {
  rec_body<1152, 0>(gxAll, actOut, WhhG, biasG, cnt, cstate, t0, TS, chrows);
}
__global__ __launch_bounds__(512, 2) void lstm_rec448(
    const unsigned short* __restrict__ gxAll, unsigned short* __restrict__ actOut,
    const unsigned short* __restrict__ WhhG, const float* __restrict__ biasG,
    unsigned int* __restrict__ cnt, float* __restrict__ cstate, int t0, int TS, int chrows) {
  rec_body<448, 0>(gxAll, actOut, WhhG, biasG, cnt, cstate, t0, TS, chrows);
}
__global__ __launch_bounds__(512, 2) void diag_sync_kernel(
    unsigned short* __restrict__ actD, unsigned int* __restrict__ cntD, int S, int chrows) {
  rec_body<1152, 1>(nullptr, actD, nullptr, nullptr, cntD, nullptr, 0, S, chrows);
}
__global__ __launch_bounds__(512, 2) void diag_comp_kernel(
    const unsigned short* __restrict__ gxAll, unsigned short* __restrict__ actD,
    const unsigned short* __restrict__ WhhG, const float* __restrict__ biasG,
    unsigned int* __restrict__ cntD, int S, int chrows) {
  rec_body<1152, 2>(gxAll, actD, WhhG, biasG, cntD, nullptr, 0, S, chrows);
}
__global__ __launch_bounds__(512, 2) void diag_nohl_kernel(
    const unsigned short* __restrict__ gxAll, unsigned short* __restrict__ actD,
    const unsigned short* __restrict__ WhhG, const float* __restrict__ biasG,
    unsigned int* __restrict__ cntD, int S, int chrows) {
  rec_body<1152, 3>(gxAll, actD, WhhG, biasG, cntD, nullptr, 0, S, chrows);
}

// ------------------------------- host ----------------------------------------
extern "C" void kernel_launch(void* const* d_in, const int* in_sizes, int n_in,
                              void* d_out, int out_size, void* d_ws, size_t ws_size,
                              hipStream_t stream) {
  (void)in_sizes; (void)n_in; (void)out_size;
  const int* x = (const int*)d_in[0];
  const void* emb = d_in[1];
  const void* wih[3] = {d_in[2], d_in[6], d_in[10]};
  const void* whh[3] = {d_in[3], d_in[7], d_in[11]};
  const void* bih[3] = {d_in[4], d_in[8], d_in[12]};
  const void* bhh[3] = {d_in[5], d_in[9], d_in[13]};

  char* ws = (char*)d_ws;
  size_t off = 0;
  unsigned short* act0 = (unsigned short*)(ws + off); off += (size_t)32768 * 448 * 2;
  unsigned short* act1 = (unsigned short*)(ws + off); off += (size_t)32768 * 1152 * 2;
  unsigned short* act2 = (unsigned short*)(ws + off); off += (size_t)32768 * 1152 * 2;
  unsigned short* act3 = act0;  // alias: act0 dead after L0 GEMM chunks
  unsigned short* WihG = (unsigned short*)(ws + off); off += (size_t)4608 * 1152 * 2;
  unsigned short* WhhG = (unsigned short*)(ws + off); off += (size_t)4608 * 1152 * 2;
  float* biasG = (float*)(ws + off); off += (size_t)4608 * 4;
  float* cstate = (float*)(ws + off); off += (size_t)64 * 1152 * 4;
  unsigned int* cnt = (unsigned int*)(ws + off); off += 4096;
  unsigned int* cntD = (unsigned int*)(ws + off); off += 4096;
  unsigned int* dflag = (unsigned int*)(ws + off); off += 256;
  unsigned short* gx = (unsigned short*)(ws + off);
  unsigned short* actD = act1;  // diag scratch alias (act1 dead at diag time)

  // gx chunk sizing from remaining workspace (589,824 B per timestep)
  size_t avail = (ws_size > off) ? (ws_size - off) : 0;
  int CH = 512;
  while (CH > 32 && (size_t)CH * 589824 > avail) CH >>= 1;
  const int chrows = CH * 64, nch = 512 / CH;
  const int diagS = 224;

  const size_t ldsrec = 2 * 64 * 68 * 4;  // 34,816 B

  probe_kernel<<<1, 256, 0, stream>>>((const unsigned int*)emb, dflag);
  embed_kernel<<<7168, 256, 0, stream>>>(x, emb, act0, dflag);

  // ---- Layer 0: din 400(->448) -> H 1150(->1152)
  prep_kernel<<<2 * 4608 + 1, 256, 0, stream>>>(wih[0], whh[0], bih[0], bhh[0],
                                                WihG, WhhG, biasG, 1150, 1152, 400, 448, dflag);
  hipMemsetAsync(cnt, 0, 4096, stream);
  for (int c = 0; c < nch; ++c) {
    gemm_xw_kernel<<<dim3(CH / 2, 36), 256, 0, stream>>>(act0 + (size_t)c * chrows * 448, WihG, gx, 448, chrows);
    lstm_rec1152<<<72, 512, ldsrec, stream>>>(gx, act1, WhhG, biasG, cnt, cstate, c * CH, CH, chrows);
  }

  // ---- Layer 1: 1150(->1152) -> 1150(->1152)
  prep_kernel<<<2 * 4608 + 1, 256, 0, stream>>>(wih[1], whh[1], bih[1], bhh[1],
                                                WihG, WhhG, biasG, 1150, 1152, 1150, 1152, dflag);
  hipMemsetAsync(cnt, 0, 4096, stream);
  for (int c = 0; c < nch; ++c) {
    gemm_xw_kernel<<<dim3(CH / 2, 36), 256, 0, stream>>>(act1 + (size_t)c * chrows * 1152, WihG, gx, 1152, chrows);
    lstm_rec1152<<<72, 512, ldsrec, stream>>>(gx, act2, WhhG, biasG, cnt, cstate, c * CH, CH, chrows);
  }

  // ---- Layer 2: 1150(->1152) -> H 400(->448)
  prep_kernel<<<2 * 1792 + 1, 256, 0, stream>>>(wih[2], whh[2], bih[2], bhh[2],
                                                WihG, WhhG, biasG, 400, 448, 1150, 1152, dflag);
  hipMemsetAsync(cnt, 0, 4096, stream);
  for (int c = 0; c < nch; ++c) {
    gemm_xw_kernel<<<dim3(CH / 2, 14), 256, 0, stream>>>(act2 + (size_t)c * chrows * 1152, WihG, gx, 1152, chrows);
    lstm_rec448<<<28, 512, ldsrec, stream>>>(gx, act3, WhhG, biasG, cnt, cstate, c * CH, CH, chrows);
  }

  unpad_kernel<<<6400, 256, 0, stream>>>(act3, d_out, dflag);

  // ---- diagnostics (scratch aliases; 3-way decomposition of the step body) --
  hipMemsetAsync(cntD, 0, 4096, stream);
  diag_sync_kernel<<<72, 512, ldsrec, stream>>>(actD, cntD, diagS, chrows);
  hipMemsetAsync(cntD, 0, 4096, stream);
  diag_comp_kernel<<<72, 512, ldsrec, stream>>>(gx, actD, WhhG, biasG, cntD, diagS, chrows);
  hipMemsetAsync(cntD, 0, 4096, stream);
  diag_nohl_kernel<<<72, 512, ldsrec, stream>>>(gx, actD, WhhG, biasG, cntD, diagS, chrows);
}

// Round 8
// 17065.915 us; speedup vs baseline: 1.7558x; 1.7558x over previous
//
#include <hip/hip_runtime.h>
#include <stdint.h>

typedef _Float16 f16x8 __attribute__((ext_vector_type(8)));
typedef _Float16 f16x4 __attribute__((ext_vector_type(4)));
typedef float f32x4 __attribute__((ext_vector_type(4)));

static __device__ __forceinline__ float bf2f(unsigned short u) {
  return __uint_as_float(((unsigned int)u) << 16);
}
static __device__ __forceinline__ unsigned short f2bf(float f) {
  unsigned int u = __float_as_uint(f);
  u = (u + 0x7FFFu + ((u >> 16) & 1u)) >> 16;  // RNE
  return (unsigned short)u;
}
static __device__ __forceinline__ unsigned short f2h(float f) {
  _Float16 h = (_Float16)f;
  return __builtin_bit_cast(unsigned short, h);
}
static __device__ __forceinline__ float h2f(unsigned short b) {
  _Float16 h = __builtin_bit_cast(_Float16, b);
  return (float)h;
}
static __device__ __forceinline__ float sigm(float x) { return 1.0f / (1.0f + __expf(-x)); }
static __device__ __forceinline__ float tanh_fast(float x) {
  float ax = fabsf(x);
  float e = __expf(-2.0f * ax);
  float r = (1.0f - e) / (1.0f + e);
  return copysignf(r, x);
}

// ---------------- dtype probe: 1 = bf16 inputs, 0 = f32 inputs ----------------
__global__ void probe_kernel(const unsigned int* __restrict__ raw, unsigned int* __restrict__ dflag) {
  __shared__ int s;
  int tid = threadIdx.x;
  if (tid == 0) s = 0;
  __syncthreads();
  int v = 0;
  for (int k = 0; k < 4; ++k) {
    unsigned int d = raw[2048 + tid * 4 + k];
    unsigned int lo = d & 0xFFFFu, ex = (lo >> 7) & 0xFFu;
    if (lo == 0u || (ex >= 0x40u && ex <= 0x7Cu)) v++;
  }
  atomicAdd(&s, v);
  __syncthreads();
  if (tid == 0) dflag[0] = (s >= 614) ? 1u : 0u;
}

// ---------------- embedding -> f16 act0 [32768][448], pad cols -> 0 ----------
__global__ void embed_kernel(const int* __restrict__ x, const void* __restrict__ emb,
                             unsigned short* __restrict__ act, const unsigned int* __restrict__ dflag) {
  int idx = blockIdx.x * 256 + threadIdx.x;  // 32768 rows * 56 chunks
  int row = idx / 56, c = idx % 56;
  unsigned short* dst = act + (size_t)row * 448 + c * 8;
  union { uint4 v; unsigned short s[8]; } o;
  if (c < 50) {
    int tok = x[row];
    if (dflag[0]) {
      const unsigned short* e = (const unsigned short*)emb + (size_t)tok * 400 + c * 8;
      union { uint4 v; unsigned short s[8]; } r; r.v = *(const uint4*)e;
#pragma unroll
      for (int k = 0; k < 8; ++k) o.s[k] = f2h(bf2f(r.s[k]));
    } else {
      const float* e = (const float*)emb + (size_t)tok * 400 + c * 8;
      float4 r0 = *(const float4*)e, r1 = *(const float4*)(e + 4);
      const float* p0 = (const float*)&r0; const float* p1 = (const float*)&r1;
#pragma unroll
      for (int k = 0; k < 4; ++k) { o.s[k] = f2h(p0[k]); o.s[4 + k] = f2h(p1[k]); }
    }
  } else {
    o.v.x = o.v.y = o.v.z = o.v.w = 0u;
  }
  *(uint4*)dst = o.v;
}

// ------------- weights/bias -> GROUP-MAJOR padded f16 layouts -----------------
// Row j = G*32 + q*8 + u  <->  unit i = G*8+u, gate q (i,f,g,o).
__global__ void prep_kernel(const void* __restrict__ wih, const void* __restrict__ whh,
                            const void* __restrict__ bih, const void* __restrict__ bhh,
                            unsigned short* __restrict__ WihG, unsigned short* __restrict__ WhhG,
                            float* __restrict__ biasG, int H, int HPo, int din, int dpIn,
                            const unsigned int* __restrict__ dflag) {
  int nb = 4 * HPo, bid = blockIdx.x, tid = threadIdx.x;
  bool isf32 = (dflag[0] == 0u);
  if (bid < 2 * nb) {
    bool ih = bid < nb;
    int j = ih ? bid : bid - nb;
    int i = (j >> 5) * 8 + (j & 7), q = (j >> 3) & 3;
    int cdst = ih ? dpIn : HPo, csrc = ih ? din : H;
    unsigned short* dst = (ih ? WihG : WhhG) + (size_t)j * cdst;
    bool valid = i < H;
    const void* w = ih ? wih : whh;
    for (int m = tid; m < cdst; m += 256) {
      unsigned short v = 0;
      if (valid && m < csrc) {
        if (isf32) v = f2h(((const float*)w)[(size_t)(q * H + i) * csrc + m]);
        else       v = f2h(bf2f(((const unsigned short*)w)[(size_t)(q * H + i) * csrc + m]));
      }
      dst[m] = v;
    }
  } else {
    for (int m = tid; m < nb; m += 256) {
      int i = (m >> 5) * 8 + (m & 7), q = (m >> 3) & 3;
      float v = 0.0f;
      if (i < H) {
        if (isf32) v = ((const float*)bih)[q * H + i] + ((const float*)bhh)[q * H + i];
        else       v = bf2f(((const unsigned short*)bih)[q * H + i]) + bf2f(((const unsigned short*)bhh)[q * H + i]);
      }
      biasG[m] = v;
    }
  }
}

// ---------------- final unpad: act3 f16 [.][448] -> d_out (bf16 or f32) -------
__global__ void unpad_kernel(const unsigned short* __restrict__ act, void* __restrict__ out,
                             const unsigned int* __restrict__ dflag) {
  int idx = blockIdx.x * 256 + threadIdx.x;  // 32768 * 50
  int row = idx / 50, c = idx % 50;
  const unsigned short* src = act + (size_t)row * 448 + c * 8;
  union { uint4 v; unsigned short s[8]; } u; u.v = *(const uint4*)src;
  if (dflag[0]) {
    union { uint4 v; unsigned short s[8]; } o;
#pragma unroll
    for (int k = 0; k < 8; ++k) o.s[k] = f2bf(h2f(u.s[k]));
    *(uint4*)((unsigned short*)out + (size_t)row * 400 + c * 8) = o.v;
  } else {
    float4 o0, o1;
    float* p0 = (float*)&o0; float* p1 = (float*)&o1;
#pragma unroll
    for (int k = 0; k < 4; ++k) { p0[k] = h2f(u.s[k]); p1[k] = h2f(u.s[4 + k]); }
    float* dst = (float*)out + (size_t)row * 400 + c * 8;
    *(float4*)dst = o0; *(float4*)(dst + 4) = o1;
  }
}

// ------------- chunked GEMM: gx = act_chunk @ WihG^T, cell-layout f16 ---------
// gx[((size_t)G*chrows + m)*32 + u*4 + q], G=n>>5, q=(n>>3)&3, u=n&7.
__global__ __launch_bounds__(256, 1) void gemm_xw_kernel(
    const unsigned short* __restrict__ A, const unsigned short* __restrict__ B,
    unsigned short* __restrict__ gx, int K, int chrows) {
  __shared__ unsigned short Asm[128 * 32], Bsm[128 * 32];  // 8KB each, XOR-swizzled
  const int tid = threadIdx.x, lane = tid & 63, wv = tid >> 6;
  const int bm0 = blockIdx.x * 128, bn0 = blockIdx.y * 128;
  f32x4 acc[2][8] = {};
  const int nkt = K >> 5;
  for (int kt = 0; kt < nkt; ++kt) {
    __syncthreads();
#pragma unroll
    for (int j = 0; j < 2; ++j) {
      int idx = tid * 2 + j, r = idx >> 2, c4 = idx & 3;
      uint4 va = *(const uint4*)(A + (size_t)(bm0 + r) * K + kt * 32 + c4 * 8);
      uint4 vb = *(const uint4*)(B + (size_t)(bn0 + r) * K + kt * 32 + c4 * 8);
      int off = (r * 64 + c4 * 16) ^ ((r & 7) << 4);
      *(uint4*)((char*)Asm + off) = va;
      *(uint4*)((char*)Bsm + off) = vb;
    }
    __syncthreads();
    f16x8 af[2], bf[8];
#pragma unroll
    for (int rt = 0; rt < 2; ++rt) {
      int arow = wv * 32 + rt * 16 + (lane & 15);
      int off = (arow * 64 + ((lane >> 4) << 4)) ^ ((arow & 7) << 4);
      af[rt] = *(const f16x8*)((char*)Asm + off);
    }
#pragma unroll
    for (int ct = 0; ct < 8; ++ct) {
      int brow = ct * 16 + (lane & 15);
      int off = (brow * 64 + ((lane >> 4) << 4)) ^ ((brow & 7) << 4);
      bf[ct] = *(const f16x8*)((char*)Bsm + off);
    }
#pragma unroll
    for (int rt = 0; rt < 2; ++rt)
#pragma unroll
      for (int ct = 0; ct < 8; ++ct)
        acc[rt][ct] = __builtin_amdgcn_mfma_f32_16x16x32_f16(af[rt], bf[ct], acc[rt][ct], 0, 0, 0);
  }
#pragma unroll
  for (int ct = 0; ct < 8; ++ct) {
    int n = bn0 + ct * 16 + (lane & 15);
    int G = n >> 5, c = n & 31;
    int cellcol = (c & 7) * 4 + (c >> 3);
#pragma unroll
    for (int rt = 0; rt < 2; ++rt) {
#pragma unroll
      for (int reg = 0; reg < 4; ++reg) {
        int m = bm0 + wv * 32 + rt * 16 + ((lane >> 4) << 2) + reg;
        gx[((size_t)G * chrows + m) * 32 + cellcol] = f2h(acc[rt][ct][reg]);
      }
    }
  }
}

// ---------------- recurrent phase: h-part only, chunked, weights in VGPR -------
// Block G owns 8 hidden units (32 gate-cols, layout q*8+u). 512 threads = 8 waves.
// HP=1152: nq=wv&1 (16-col half), kq=wv>>1 (4 k-quarters, KT=9), MT=4 m-tiles.
// HP=448 : nq=wv&1, kq=(wv>>1)&1 (2 k-halves, KT=7), mh=wv>>2, MT=2 m-tiles.
// Per step: ONE burst of MT*KT h-loads (single exposed latency), MFMA, LDS-only
// barrier (keeps gx load in flight), reduce+gates, publish, vmcnt-drain barrier,
// release arrival counter.
template <int HP, int KQ, int MH>
static __device__ __forceinline__ void rec_body(
    const unsigned short* __restrict__ gxAll, unsigned short* __restrict__ actOut,
    const unsigned short* __restrict__ WhhG, const float* __restrict__ biasG,
    unsigned int* __restrict__ cnt, float* __restrict__ cstate,
    int t0, int TS, int chrows) {
  constexpr int NB = HP / 8;               // blocks
  constexpr unsigned PERQ = (unsigned)(NB / 8);
  constexpr int KS = HP / KQ;              // k per slice
  constexpr int KT = KS / 32;              // k-tiles per wave (9 or 7)
  constexpr int MT = 4 / MH;               // m-tiles per wave
  constexpr int GSTR = 36;                 // conflict-free reduce reads
  extern __shared__ char smem[];
  float* Gp = (float*)smem;                // [KQ][64][GSTR] f32
  const int tid = threadIdx.x, lane = tid & 63, wv = tid >> 6;
  const int nq = wv & 1, rr = wv >> 1;
  const int kq = (MH == 1) ? rr : (rr & (KQ - 1));
  const int mh = (MH == 1) ? 0 : (rr >> 1);
  const int lrow = lane & 15, kc8 = (lane >> 4) << 3;
  const int G = blockIdx.x;
  const int urow = tid >> 3, ui = tid & 7;

  float bs[4];
  float creg = 0.0f;
  f16x8 wreg[KT];
  {
    const unsigned short* wp = WhhG + ((size_t)(G * 32 + nq * 16 + lrow)) * HP + kq * KS + kc8;
#pragma unroll
    for (int kt = 0; kt < KT; ++kt) wreg[kt] = *(const f16x8*)(wp + kt * 32);
#pragma unroll
    for (int q = 0; q < 4; ++q) bs[q] = biasG[G * 32 + q * 8 + ui];
    if (t0 > 0) creg = cstate[urow * HP + G * 8 + ui];
  }
  __syncthreads();

  const int tend = t0 + TS;
  for (int t = t0; t < tend; ++t) {
    // ---- wait for all blocks' h(t-1)
    if (t > 0) {
      while (true) {
        int ok = 1;
        if (tid < 8)
          ok = (__hip_atomic_load(cnt + tid * 32, __ATOMIC_RELAXED, __HIP_MEMORY_SCOPE_AGENT) >= PERQ * (unsigned)t);
        if (__syncthreads_and(ok)) break;
        __builtin_amdgcn_s_sleep(1);
      }
      asm volatile("" ::: "memory");
    }
    // ---- issue gx(t) load now; consumed in reduce, hides under MFMA phase
    f16x4 gxv = *(const f16x4*)(gxAll + ((size_t)G * chrows + (t - t0) * 64 + urow) * 32 + ui * 4);
    // ---- h-part: burst-load ALL fragments, then MFMA
    if (t > 0) {
      f16x8 hv[MT][KT];
      const unsigned short* hbase = actOut + (size_t)(t - 1) * 64 * HP + kq * KS + kc8;
#pragma unroll
      for (int mt = 0; mt < MT; ++mt) {
        const unsigned short* hp = hbase + (size_t)((mh * MT + mt) * 16 + lrow) * HP;
#pragma unroll
        for (int kt = 0; kt < KT; ++kt) hv[mt][kt] = *(const f16x8*)(hp + kt * 32);
      }
#pragma unroll
      for (int mt = 0; mt < MT; ++mt) {
        f32x4 a = {0.f, 0.f, 0.f, 0.f};
#pragma unroll
        for (int kt = 0; kt < KT; ++kt)
          a = __builtin_amdgcn_mfma_f32_16x16x32_f16(hv[mt][kt], wreg[kt], a, 0, 0, 0);
        const int br = (mh * MT + mt) * 16 + (lane >> 4) * 4;
#pragma unroll
        for (int r = 0; r < 4; ++r)
          Gp[(kq * 64 + br + r) * GSTR + nq * 16 + lrow] = a[r];
      }
    }
    // ---- LDS-only barrier: gx load stays in flight (no vmcnt drain)
    asm volatile("s_waitcnt lgkmcnt(0)" ::: "memory");
    __builtin_amdgcn_s_barrier();
    __builtin_amdgcn_sched_barrier(0);
    // ---- reduce + gate update (one unit per thread)
    float gi = (float)gxv[0] + bs[0], gf = (float)gxv[1] + bs[1];
    float gg = (float)gxv[2] + bs[2], go = (float)gxv[3] + bs[3];
    if (t > 0) {
#pragma unroll
      for (int k = 0; k < KQ; ++k) {
        const int base = (k * 64 + urow) * GSTR + ui;
        gi += Gp[base];
        gf += Gp[base + 8];
        gg += Gp[base + 16];
        go += Gp[base + 24];
      }
    }
    float ig = sigm(gi), fg = sigm(gf), gt = tanh_fast(gg), og = sigm(go);
    creg = fg * creg + ig * gt;
    unsigned short hb = f2h(og * tanh_fast(creg));
    int other = __shfl_xor((int)hb, 1);
    if ((ui & 1) == 0) {
      unsigned int pk = ((unsigned)hb & 0xFFFFu) | ((unsigned)other << 16);
      __hip_atomic_store((unsigned int*)(actOut + ((size_t)t * 64 + urow) * HP + G * 8 + ui),
                         pk, __ATOMIC_RELAXED, __HIP_MEMORY_SCOPE_AGENT);
    }
    // ---- drain h stores, sync, release arrival
    asm volatile("s_waitcnt vmcnt(0)" ::: "memory");
    __syncthreads();
    if (tid == 0)
      __hip_atomic_fetch_add(cnt + (G & 7) * 32, 1u, __ATOMIC_RELEASE, __HIP_MEMORY_SCOPE_AGENT);
  }
  cstate[urow * HP + G * 8 + ui] = creg;
}

__global__ __launch_bounds__(512, 1) void lstm_rec1152(
    const unsigned short* __restrict__ gxAll, unsigned short* __restrict__ actOut,
    const unsigned short* __restrict__ WhhG, const float* __restrict__ biasG,
    unsigned int* __restrict__ cnt, float* __restrict__ cstate, int t0, int TS, int chrows) {
  rec_body<1152, 4, 1>(gxAll, actOut, WhhG, biasG, cnt, cstate, t0, TS, chrows);
}
__global__ __launch_bounds__(512, 1) void lstm_rec448(
    const unsigned short* __restrict__ gxAll, unsigned short* __restrict__ actOut,
    const unsigned short* __restrict__ WhhG, const float* __restrict__ biasG,
    unsigned int* __restrict__ cnt, float* __restrict__ cstate, int t0, int TS, int chrows) {
  rec_body<448, 2, 2>(gxAll, actOut, WhhG, biasG, cnt, cstate, t0, TS, chrows);
}

// ------------------------------- host ----------------------------------------
extern "C" void kernel_launch(void* const* d_in, const int* in_sizes, int n_in,
                              void* d_out, int out_size, void* d_ws, size_t ws_size,
                              hipStream_t stream) {
  (void)in_sizes; (void)n_in; (void)out_size;
  const int* x = (const int*)d_in[0];
  const void* emb = d_in[1];
  const void* wih[3] = {d_in[2], d_in[6], d_in[10]};
  const void* whh[3] = {d_in[3], d_in[7], d_in[11]};
  const void* bih[3] = {d_in[4], d_in[8], d_in[12]};
  const void* bhh[3] = {d_in[5], d_in[9], d_in[13]};

  char* ws = (char*)d_ws;
  size_t off = 0;
  unsigned short* act0 = (unsigned short*)(ws + off); off += (size_t)32768 * 448 * 2;
  unsigned short* act1 = (unsigned short*)(ws + off); off += (size_t)32768 * 1152 * 2;
  unsigned short* act2 = (unsigned short*)(ws + off); off += (size_t)32768 * 1152 * 2;
  unsigned short* act3 = act0;  // alias: act0 dead after L0 GEMM chunks
  unsigned short* WihG = (unsigned short*)(ws + off); off += (size_t)4608 * 1152 * 2;
  unsigned short* WhhG = (unsigned short*)(ws + off); off += (size_t)4608 * 1152 * 2;
  float* biasG = (float*)(ws + off); off += (size_t)4608 * 4;
  float* cstate = (float*)(ws + off); off += (size_t)64 * 1152 * 4;
  unsigned int* cnt = (unsigned int*)(ws + off); off += 4096;
  unsigned int* dflag = (unsigned int*)(ws + off); off += 256;
  unsigned short* gx = (unsigned short*)(ws + off);

  // gx chunk sizing from remaining workspace (589,824 B per timestep)
  size_t avail = (ws_size > off) ? (ws_size - off) : 0;
  int CH = 512;
  while (CH > 32 && (size_t)CH * 589824 > avail) CH >>= 1;
  const int chrows = CH * 64, nch = 512 / CH;

  const size_t lds1152 = 4 * 64 * 36 * 4;  // 36,864 B
  const size_t lds448 = 2 * 64 * 36 * 4;   // 18,432 B

  probe_kernel<<<1, 256, 0, stream>>>((const unsigned int*)emb, dflag);
  embed_kernel<<<7168, 256, 0, stream>>>(x, emb, act0, dflag);

  // ---- Layer 0: din 400(->448) -> H 1150(->1152)
  prep_kernel<<<2 * 4608 + 1, 256, 0, stream>>>(wih[0], whh[0], bih[0], bhh[0],
                                                WihG, WhhG, biasG, 1150, 1152, 400, 448, dflag);
  hipMemsetAsync(cnt, 0, 4096, stream);
  for (int c = 0; c < nch; ++c) {
    gemm_xw_kernel<<<dim3(CH / 2, 36), 256, 0, stream>>>(act0 + (size_t)c * chrows * 448, WihG, gx, 448, chrows);
    lstm_rec1152<<<144, 512, lds1152, stream>>>(gx, act1, WhhG, biasG, cnt, cstate, c * CH, CH, chrows);
  }

  // ---- Layer 1: 1150(->1152) -> 1150(->1152)
  prep_kernel<<<2 * 4608 + 1, 256, 0, stream>>>(wih[1], whh[1], bih[1], bhh[1],
                                                WihG, WhhG, biasG, 1150, 1152, 1150, 1152, dflag);
  hipMemsetAsync(cnt, 0, 4096, stream);
  for (int c = 0; c < nch; ++c) {
    gemm_xw_kernel<<<dim3(CH / 2, 36), 256, 0, stream>>>(act1 + (size_t)c * chrows * 1152, WihG, gx, 1152, chrows);
    lstm_rec1152<<<144, 512, lds1152, stream>>>(gx, act2, WhhG, biasG, cnt, cstate, c * CH, CH, chrows);
  }

  // ---- Layer 2: 1150(->1152) -> H 400(->448)
  prep_kernel<<<2 * 1792 + 1, 256, 0, stream>>>(wih[2], whh[2], bih[2], bhh[2],
                                                WihG, WhhG, biasG, 400, 448, 1150, 1152, dflag);
  hipMemsetAsync(cnt, 0, 4096, stream);
  for (int c = 0; c < nch; ++c) {
    gemm_xw_kernel<<<dim3(CH / 2, 14), 256, 0, stream>>>(act2 + (size_t)c * chrows * 1152, WihG, gx, 1152, chrows);
    lstm_rec448<<<56, 512, lds448, stream>>>(gx, act3, WhhG, biasG, cnt, cstate, c * CH, CH, chrows);
  }

  unpad_kernel<<<6400, 256, 0, stream>>>(act3, d_out, dflag);
}

// Round 9
// 10040.227 us; speedup vs baseline: 2.9844x; 1.6998x over previous
//
#include <hip/hip_runtime.h>
#include <stdint.h>

typedef _Float16 f16x8 __attribute__((ext_vector_type(8)));
typedef _Float16 f16x4 __attribute__((ext_vector_type(4)));
typedef float f32x4 __attribute__((ext_vector_type(4)));

static __device__ __forceinline__ float bf2f(unsigned short u) {
  return __uint_as_float(((unsigned int)u) << 16);
}
static __device__ __forceinline__ unsigned short f2bf(float f) {
  unsigned int u = __float_as_uint(f);
  u = (u + 0x7FFFu + ((u >> 16) & 1u)) >> 16;  // RNE
  return (unsigned short)u;
}
static __device__ __forceinline__ unsigned short f2h(float f) {
  _Float16 h = (_Float16)f;
  return __builtin_bit_cast(unsigned short, h);
}
static __device__ __forceinline__ float h2f(unsigned short b) {
  _Float16 h = __builtin_bit_cast(_Float16, b);
  return (float)h;
}
static __device__ __forceinline__ float sigm(float x) { return 1.0f / (1.0f + __expf(-x)); }
static __device__ __forceinline__ float tanh_fast(float x) {
  float ax = fabsf(x);
  float e = __expf(-2.0f * ax);
  float r = (1.0f - e) / (1.0f + e);
  return copysignf(r, x);
}

// ---------------- dtype probe: 1 = bf16 inputs, 0 = f32 inputs ----------------
__global__ void probe_kernel(const unsigned int* __restrict__ raw, unsigned int* __restrict__ dflag) {
  __shared__ int s;
  int tid = threadIdx.x;
  if (tid == 0) s = 0;
  __syncthreads();
  int v = 0;
  for (int k = 0; k < 4; ++k) {
    unsigned int d = raw[2048 + tid * 4 + k];
    unsigned int lo = d & 0xFFFFu, ex = (lo >> 7) & 0xFFu;
    if (lo == 0u || (ex >= 0x40u && ex <= 0x7Cu)) v++;
  }
  atomicAdd(&s, v);
  __syncthreads();
  if (tid == 0) dflag[0] = (s >= 614) ? 1u : 0u;
}

// ---------------- embedding -> f16 act0 [32768][448], pad cols -> 0 ----------
__global__ void embed_kernel(const int* __restrict__ x, const void* __restrict__ emb,
                             unsigned short* __restrict__ act, const unsigned int* __restrict__ dflag) {
  int idx = blockIdx.x * 256 + threadIdx.x;  // 32768 rows * 56 chunks
  int row = idx / 56, c = idx % 56;
  unsigned short* dst = act + (size_t)row * 448 + c * 8;
  union { uint4 v; unsigned short s[8]; } o;
  if (c < 50) {
    int tok = x[row];
    if (dflag[0]) {
      const unsigned short* e = (const unsigned short*)emb + (size_t)tok * 400 + c * 8;
      union { uint4 v; unsigned short s[8]; } r; r.v = *(const uint4*)e;
#pragma unroll
      for (int k = 0; k < 8; ++k) o.s[k] = f2h(bf2f(r.s[k]));
    } else {
      const float* e = (const float*)emb + (size_t)tok * 400 + c * 8;
      float4 r0 = *(const float4*)e, r1 = *(const float4*)(e + 4);
      const float* p0 = (const float*)&r0; const float* p1 = (const float*)&r1;
#pragma unroll
      for (int k = 0; k < 4; ++k) { o.s[k] = f2h(p0[k]); o.s[4 + k] = f2h(p1[k]); }
    }
  } else {
    o.v.x = o.v.y = o.v.z = o.v.w = 0u;
  }
  *(uint4*)dst = o.v;
}

// ------------- weights/bias -> GROUP-MAJOR padded f16 layouts -----------------
// Row j = G*64 + q*16 + u  <->  unit i = G*16+u, gate q (i,f,g,o).
__global__ void prep_kernel(const void* __restrict__ wih, const void* __restrict__ whh,
                            const void* __restrict__ bih, const void* __restrict__ bhh,
                            unsigned short* __restrict__ WihG, unsigned short* __restrict__ WhhG,
                            float* __restrict__ biasG, int H, int HPo, int din, int dpIn,
                            const unsigned int* __restrict__ dflag) {
  int nb = 4 * HPo, bid = blockIdx.x, tid = threadIdx.x;
  bool isf32 = (dflag[0] == 0u);
  if (bid < 2 * nb) {
    bool ih = bid < nb;
    int j = ih ? bid : bid - nb;
    int i = (j >> 6) * 16 + (j & 15), q = (j >> 4) & 3;
    int cdst = ih ? dpIn : HPo, csrc = ih ? din : H;
    unsigned short* dst = (ih ? WihG : WhhG) + (size_t)j * cdst;
    bool valid = i < H;
    const void* w = ih ? wih : whh;
    for (int m = tid; m < cdst; m += 256) {
      unsigned short v = 0;
      if (valid && m < csrc) {
        if (isf32) v = f2h(((const float*)w)[(size_t)(q * H + i) * csrc + m]);
        else       v = f2h(bf2f(((const unsigned short*)w)[(size_t)(q * H + i) * csrc + m]));
      }
      dst[m] = v;
    }
  } else {
    for (int m = tid; m < nb; m += 256) {
      int i = (m >> 6) * 16 + (m & 15), q = (m >> 4) & 3;
      float v = 0.0f;
      if (i < H) {
        if (isf32) v = ((const float*)bih)[q * H + i] + ((const float*)bhh)[q * H + i];
        else       v = bf2f(((const unsigned short*)bih)[q * H + i]) + bf2f(((const unsigned short*)bhh)[q * H + i]);
      }
      biasG[m] = v;
    }
  }
}

// ---------------- final unpad: act3 f16 [.][448] -> d_out (bf16 or f32) -------
__global__ void unpad_kernel(const unsigned short* __restrict__ act, void* __restrict__ out,
                             const unsigned int* __restrict__ dflag) {
  int idx = blockIdx.x * 256 + threadIdx.x;  // 32768 * 50
  int row = idx / 50, c = idx % 50;
  const unsigned short* src = act + (size_t)row * 448 + c * 8;
  union { uint4 v; unsigned short s[8]; } u; u.v = *(const uint4*)src;
  if (dflag[0]) {
    union { uint4 v; unsigned short s[8]; } o;
#pragma unroll
    for (int k = 0; k < 8; ++k) o.s[k] = f2bf(h2f(u.s[k]));
    *(uint4*)((unsigned short*)out + (size_t)row * 400 + c * 8) = o.v;
  } else {
    float4 o0, o1;
    float* p0 = (float*)&o0; float* p1 = (float*)&o1;
#pragma unroll
    for (int k = 0; k < 4; ++k) { p0[k] = h2f(u.s[k]); p1[k] = h2f(u.s[4 + k]); }
    float* dst = (float*)out + (size_t)row * 400 + c * 8;
    *(float4*)dst = o0; *(float4*)(dst + 4) = o1;
  }
}

// ------------- chunked GEMM: gx = act_chunk @ WihG^T, cell-layout f16 ---------
// gx[((size_t)G*chrows + m)*64 + u*4 + q], G=n>>6, q=(n>>4)&3, u=n&15.
__global__ __launch_bounds__(256, 1) void gemm_xw_kernel(
    const unsigned short* __restrict__ A, const unsigned short* __restrict__ B,
    unsigned short* __restrict__ gx, int K, int chrows) {
  __shared__ unsigned short Asm[128 * 32], Bsm[128 * 32];  // 8KB each, XOR-swizzled
  const int tid = threadIdx.x, lane = tid & 63, wv = tid >> 6;
  const int bm0 = blockIdx.x * 128, bn0 = blockIdx.y * 128;
  f32x4 acc[2][8] = {};
  const int nkt = K >> 5;
  for (int kt = 0; kt < nkt; ++kt) {
    __syncthreads();
#pragma unroll
    for (int j = 0; j < 2; ++j) {
      int idx = tid * 2 + j, r = idx >> 2, c4 = idx & 3;
      uint4 va = *(const uint4*)(A + (size_t)(bm0 + r) * K + kt * 32 + c4 * 8);
      uint4 vb = *(const uint4*)(B + (size_t)(bn0 + r) * K + kt * 32 + c4 * 8);
      int off = (r * 64 + c4 * 16) ^ ((r & 7) << 4);
      *(uint4*)((char*)Asm + off) = va;
      *(uint4*)((char*)Bsm + off) = vb;
    }
    __syncthreads();
    f16x8 af[2], bf[8];
#pragma unroll
    for (int rt = 0; rt < 2; ++rt) {
      int arow = wv * 32 + rt * 16 + (lane & 15);
      int off = (arow * 64 + ((lane >> 4) << 4)) ^ ((arow & 7) << 4);
      af[rt] = *(const f16x8*)((char*)Asm + off);
    }
#pragma unroll
    for (int ct = 0; ct < 8; ++ct) {
      int brow = ct * 16 + (lane & 15);
      int off = (brow * 64 + ((lane >> 4) << 4)) ^ ((brow & 7) << 4);
      bf[ct] = *(const f16x8*)((char*)Bsm + off);
    }
#pragma unroll
    for (int rt = 0; rt < 2; ++rt)
#pragma unroll
      for (int ct = 0; ct < 8; ++ct)
        acc[rt][ct] = __builtin_amdgcn_mfma_f32_16x16x32_f16(af[rt], bf[ct], acc[rt][ct], 0, 0, 0);
  }
#pragma unroll
  for (int ct = 0; ct < 8; ++ct) {
    int n = bn0 + ct * 16 + (lane & 15);
    int G = n >> 6, c = n & 63;
    int cellcol = (c & 15) * 4 + (c >> 4);
#pragma unroll
    for (int rt = 0; rt < 2; ++rt) {
#pragma unroll
      for (int reg = 0; reg < 4; ++reg) {
        int m = bm0 + wv * 32 + rt * 16 + ((lane >> 4) << 2) + reg;
        gx[((size_t)G * chrows + m) * 64 + cellcol] = f2h(acc[rt][ct][reg]);
      }
    }
  }
}

// ---------------- recurrent phase: 16 units x 32 rows per block ----------------
// Grid = 2*NB blocks: G = bid>>1 (unit group), bh = bid&1 (batch-row half).
// Row-halves are INDEPENDENT recurrences -> separate arrival-counter groups.
// 8 waves: kq = wv%KQW (k slice), nq = (wv/KQW)%NQ (col slice), mh = wv/(KQW*NQ)
// (16-row half of the 32). Per wave: 1 m-tile x KT k-tiles x CF col-frags.
// Per-CU h read: 32 rows x HP cols (73.7 KB @1152), no duplication when NQ=1.
template <int HP, int KQW, int NQ, int NCNT>
static __device__ __forceinline__ void rec_body(
    const unsigned short* __restrict__ gxAll, unsigned short* __restrict__ actOut,
    const unsigned short* __restrict__ WhhG, const float* __restrict__ biasG,
    unsigned int* __restrict__ cnt, float* __restrict__ cstate,
    int t0, int TS, int chrows) {
  constexpr int NB = HP / 16;              // blocks per row-half
  constexpr unsigned PERQ = (unsigned)(NB / NCNT);
  constexpr int KS = HP / KQW;             // k per slice
  constexpr int KT = KS / 32;              // k-tiles per wave
  constexpr int CF = 4 / NQ;               // 16-col fragments per wave
  constexpr int GSTR = 68;
  extern __shared__ char smem[];
  float* Gp = (float*)smem;                // [KQW*32][GSTR] f32
  const int tid = threadIdx.x, lane = tid & 63, wv = tid >> 6;
  const int kq = wv % KQW, t2 = wv / KQW;
  const int nq = t2 % NQ, mh = t2 / NQ;
  const int lrow = lane & 15, kc8 = (lane >> 4) << 3;
  const int G = blockIdx.x >> 1, bh = blockIdx.x & 1;
  const int urow = tid >> 4, ui = tid & 15;     // reduce cell: row urow, unit ui
  unsigned int* mycnt = cnt + (size_t)bh * 8 * 32;

  float bs[4];
  float creg = 0.0f;
  f16x8 wreg[CF][KT];
  {
    const unsigned short* wbase = WhhG + (size_t)G * 64 * HP + kq * KS + kc8;
#pragma unroll
    for (int cf = 0; cf < CF; ++cf) {
      const unsigned short* wp = wbase + (size_t)((nq * CF + cf) * 16 + lrow) * HP;
#pragma unroll
      for (int kt = 0; kt < KT; ++kt) wreg[cf][kt] = *(const f16x8*)(wp + kt * 32);
    }
#pragma unroll
    for (int q = 0; q < 4; ++q) bs[q] = biasG[G * 64 + q * 16 + ui];
    if (t0 > 0) creg = cstate[(bh * 32 + urow) * HP + G * 16 + ui];
  }
  __syncthreads();

  const int tend = t0 + TS;
  for (int t = t0; t < tend; ++t) {
    // ---- wait for this row-half's blocks to publish h(t-1)
    if (t > 0) {
      while (true) {
        int ok = 1;
        if (tid < NCNT)
          ok = (__hip_atomic_load(mycnt + tid * 32, __ATOMIC_RELAXED, __HIP_MEMORY_SCOPE_AGENT) >= PERQ * (unsigned)t);
        if (__syncthreads_and(ok)) break;
        __builtin_amdgcn_s_sleep(1);
      }
      asm volatile("" ::: "memory");
    }
    // ---- issue gx(t) load now; consumed in reduce, hides under MFMA phase
    f16x4 gxv = *(const f16x4*)(gxAll + ((size_t)G * chrows + (t - t0) * 64 + bh * 32 + urow) * 64 + ui * 4);
    // ---- h-part: burst-load this wave's 16 rows x k-slice, then MFMA
    if (t > 0) {
      f16x8 hv[KT];
      const unsigned short* hp =
          actOut + ((size_t)(t - 1) * 64 + bh * 32 + mh * 16 + lrow) * HP + kq * KS + kc8;
#pragma unroll
      for (int kt = 0; kt < KT; ++kt) hv[kt] = *(const f16x8*)(hp + kt * 32);
      f32x4 a[CF];
#pragma unroll
      for (int cf = 0; cf < CF; ++cf) a[cf] = f32x4{0.f, 0.f, 0.f, 0.f};
#pragma unroll
      for (int kt = 0; kt < KT; ++kt)
#pragma unroll
        for (int cf = 0; cf < CF; ++cf)
          a[cf] = __builtin_amdgcn_mfma_f32_16x16x32_f16(hv[kt], wreg[cf][kt], a[cf], 0, 0, 0);
      const int br = kq * 32 + mh * 16 + (lane >> 4) * 4;
#pragma unroll
      for (int cf = 0; cf < CF; ++cf)
#pragma unroll
        for (int r = 0; r < 4; ++r)
          Gp[(br + r) * GSTR + (nq * CF + cf) * 16 + (lane & 15)] = a[cf][r];
    }
    // ---- LDS-only barrier: gx load stays in flight (no vmcnt drain)
    asm volatile("s_waitcnt lgkmcnt(0)" ::: "memory");
    __builtin_amdgcn_s_barrier();
    __builtin_amdgcn_sched_barrier(0);
    // ---- reduce + gate update (one unit per thread)
    float gi = (float)gxv[0] + bs[0], gf = (float)gxv[1] + bs[1];
    float gg = (float)gxv[2] + bs[2], go = (float)gxv[3] + bs[3];
    if (t > 0) {
#pragma unroll
      for (int k = 0; k < KQW; ++k) {
        const int base = (k * 32 + urow) * GSTR + ui;
        gi += Gp[base];
        gf += Gp[base + 16];
        gg += Gp[base + 32];
        go += Gp[base + 48];
      }
    }
    float ig = sigm(gi), fg = sigm(gf), gt = tanh_fast(gg), og = sigm(go);
    creg = fg * creg + ig * gt;
    unsigned short hb = f2h(og * tanh_fast(creg));
    int other = __shfl_xor((int)hb, 1);
    if ((ui & 1) == 0) {
      unsigned int pk = ((unsigned)hb & 0xFFFFu) | ((unsigned)other << 16);
      __hip_atomic_store((unsigned int*)(actOut + ((size_t)t * 64 + bh * 32 + urow) * HP + G * 16 + ui),
                         pk, __ATOMIC_RELAXED, __HIP_MEMORY_SCOPE_AGENT);
    }
    // ---- drain h stores, sync, release arrival
    asm volatile("s_waitcnt vmcnt(0)" ::: "memory");
    __syncthreads();
    if (tid == 0)
      __hip_atomic_fetch_add(mycnt + (G % NCNT) * 32, 1u, __ATOMIC_RELEASE, __HIP_MEMORY_SCOPE_AGENT);
  }
  cstate[(bh * 32 + urow) * HP + G * 16 + ui] = creg;
}

__global__ __launch_bounds__(512, 1) void lstm_rec1152(
    const unsigned short* __restrict__ gxAll, unsigned short* __restrict__ actOut,
    const unsigned short* __restrict__ WhhG, const float* __restrict__ biasG,
    unsigned int* __restrict__ cnt, float* __restrict__ cstate, int t0, int TS, int chrows) {
  rec_body<1152, 4, 1, 8>(gxAll, actOut, WhhG, biasG, cnt, cstate, t0, TS, chrows);
}
__global__ __launch_bounds__(512, 1) void lstm_rec448(
    const unsigned short* __restrict__ gxAll, unsigned short* __restrict__ actOut,
    const unsigned short* __restrict__ WhhG, const float* __restrict__ biasG,
    unsigned int* __restrict__ cnt, float* __restrict__ cstate, int t0, int TS, int chrows) {
  rec_body<448, 2, 2, 4>(gxAll, actOut, WhhG, biasG, cnt, cstate, t0, TS, chrows);
}

// ------------------------------- host ----------------------------------------
extern "C" void kernel_launch(void* const* d_in, const int* in_sizes, int n_in,
                              void* d_out, int out_size, void* d_ws, size_t ws_size,
                              hipStream_t stream) {
  (void)in_sizes; (void)n_in; (void)out_size;
  const int* x = (const int*)d_in[0];
  const void* emb = d_in[1];
  const void* wih[3] = {d_in[2], d_in[6], d_in[10]};
  const void* whh[3] = {d_in[3], d_in[7], d_in[11]};
  const void* bih[3] = {d_in[4], d_in[8], d_in[12]};
  const void* bhh[3] = {d_in[5], d_in[9], d_in[13]};

  char* ws = (char*)d_ws;
  size_t off = 0;
  unsigned short* act0 = (unsigned short*)(ws + off); off += (size_t)32768 * 448 * 2;
  unsigned short* act1 = (unsigned short*)(ws + off); off += (size_t)32768 * 1152 * 2;
  unsigned short* act2 = (unsigned short*)(ws + off); off += (size_t)32768 * 1152 * 2;
  unsigned short* act3 = act0;  // alias: act0 dead after L0 GEMM chunks
  unsigned short* WihG = (unsigned short*)(ws + off); off += (size_t)4608 * 1152 * 2;
  unsigned short* WhhG = (unsigned short*)(ws + off); off += (size_t)4608 * 1152 * 2;
  float* biasG = (float*)(ws + off); off += (size_t)4608 * 4;
  float* cstate = (float*)(ws + off); off += (size_t)64 * 1152 * 4;
  unsigned int* cnt = (unsigned int*)(ws + off); off += 4096;
  unsigned int* dflag = (unsigned int*)(ws + off); off += 256;
  unsigned short* gx = (unsigned short*)(ws + off);

  // gx chunk sizing from remaining workspace (589,824 B per timestep)
  size_t avail = (ws_size > off) ? (ws_size - off) : 0;
  int CH = 512;
  while (CH > 32 && (size_t)CH * 589824 > avail) CH >>= 1;
  const int chrows = CH * 64, nch = 512 / CH;

  const size_t lds1152 = 128 * 68 * 4;  // 34,816 B
  const size_t lds448 = 64 * 68 * 4;    // 17,408 B

  probe_kernel<<<1, 256, 0, stream>>>((const unsigned int*)emb, dflag);
  embed_kernel<<<7168, 256, 0, stream>>>(x, emb, act0, dflag);

  // ---- Layer 0: din 400(->448) -> H 1150(->1152)
  prep_kernel<<<2 * 4608 + 1, 256, 0, stream>>>(wih[0], whh[0], bih[0], bhh[0],
                                                WihG, WhhG, biasG, 1150, 1152, 400, 448, dflag);
  hipMemsetAsync(cnt, 0, 4096, stream);
  for (int c = 0; c < nch; ++c) {
    gemm_xw_kernel<<<dim3(CH / 2, 36), 256, 0, stream>>>(act0 + (size_t)c * chrows * 448, WihG, gx, 448, chrows);
    lstm_rec1152<<<144, 512, lds1152, stream>>>(gx, act1, WhhG, biasG, cnt, cstate, c * CH, CH, chrows);
  }

  // ---- Layer 1: 1150(->1152) -> 1150(->1152)
  prep_kernel<<<2 * 4608 + 1, 256, 0, stream>>>(wih[1], whh[1], bih[1], bhh[1],
                                                WihG, WhhG, biasG, 1150, 1152, 1150, 1152, dflag);
  hipMemsetAsync(cnt, 0, 4096, stream);
  for (int c = 0; c < nch; ++c) {
    gemm_xw_kernel<<<dim3(CH / 2, 36), 256, 0, stream>>>(act1 + (size_t)c * chrows * 1152, WihG, gx, 1152, chrows);
    lstm_rec1152<<<144, 512, lds1152, stream>>>(gx, act2, WhhG, biasG, cnt, cstate, c * CH, CH, chrows);
  }

  // ---- Layer 2: 1150(->1152) -> H 400(->448)
  prep_kernel<<<2 * 1792 + 1, 256, 0, stream>>>(wih[2], whh[2], bih[2], bhh[2],
                                                WihG, WhhG, biasG, 400, 448, 1150, 1152, dflag);
  hipMemsetAsync(cnt, 0, 4096, stream);
  for (int c = 0; c < nch; ++c) {
    gemm_xw_kernel<<<dim3(CH / 2, 14), 256, 0, stream>>>(act2 + (size_t)c * chrows * 1152, WihG, gx, 1152, chrows);
    lstm_rec448<<<56, 512, lds448, stream>>>(gx, act3, WhhG, biasG, cnt, cstate, c * CH, CH, chrows);
  }

  unpad_kernel<<<6400, 256, 0, stream>>>(act3, d_out, dflag);
}